// Round 2
// baseline (1188.917 us; speedup 1.0000x reference)
//
#include <hip/hip_runtime.h>
#include <math.h>

#define EPSf 1e-5f

// Problem constants
// x: (64,64,300,25); A: (3,25,25); conv_a/b_w: (3,16,64); conv_d_w: (3,64,64)
// out: (64,64,300,25)

// ---------------------------------------------------------------------------
// k_tr: transpose conv_d_w (S,OC,C) -> wdT (S,C,OC) so stage-2 reads are
// contiguous float4 per lane.
// ---------------------------------------------------------------------------
__global__ __launch_bounds__(256) void k_tr(const float* __restrict__ wd,
                                            float* __restrict__ wdT) {
  int idx = blockIdx.x * 256 + threadIdx.x;
  if (idx < 3 * 64 * 64) {
    int s = idx >> 12, r = idx & 4095, c = r >> 6, o = r & 63;
    wdT[idx] = wd[(s * 64 + o) * 64 + c];
  }
}

// ---------------------------------------------------------------------------
// k_M: fused  a = tanh(bn_a(x @ wa^T)), b = tanh(bn_b(x @ wb^T)),
//             M += a^T b   (per (n,s), accumulated over t-chunks, atomicAdd)
// grid (5 t-chunks, 3 s, 64 n), block 256 (4 waves).
// Wave w computes 8 rows of [a;b] (weights via wave-uniform s_loads).
// ---------------------------------------------------------------------------
__global__ __launch_bounds__(256) void k_M(
    const float* __restrict__ x,
    const float* __restrict__ wa, const float* __restrict__ wab,
    const float* __restrict__ wb, const float* __restrict__ wbb,
    const float* __restrict__ ga, const float* __restrict__ bea,
    const float* __restrict__ ma, const float* __restrict__ va,
    const float* __restrict__ gb, const float* __restrict__ beb,
    const float* __restrict__ mb, const float* __restrict__ vb,
    float* __restrict__ Mbuf) {
  __shared__ float x_lds[64 * 100];   // [c][tv]  (4 t's of 25 v)
  __shared__ float ab_lds[32 * 100 + 8];  // rows 0..15 = a, 16..31 = b (+pad)

  const int tid = threadIdx.x;
  const int lane = tid & 63;
  const int wid = __builtin_amdgcn_readfirstlane(tid >> 6);  // 0..3, uniform
  const int n = blockIdx.z, s = blockIdx.y;
  const int t_blk = blockIdx.x * 60;

  const int isB = wid >> 1;         // waves 0,1 -> a ; 2,3 -> b
  const int r0 = (wid & 1) * 8;     // row offset within a (or b)
  const float* W = (isB ? wb : wa) + (size_t)(s * 16 + r0) * 64;

  // fold bn + conv bias:  tanh(sc*conv + sh)
  float scv[8], shv[8];
  {
    const float* g_ = isB ? gb : ga;
    const float* be_ = isB ? beb : bea;
    const float* m_ = isB ? mb : ma;
    const float* v_ = isB ? vb : va;
    const float* bi_ = isB ? wbb : wab;
#pragma unroll
    for (int r = 0; r < 8; ++r) {
      int i = s * 16 + r0 + r;
      float sc = g_[i] * rsqrtf(v_[i] + EPSf);
      scv[r] = sc;
      shv[r] = (bi_[i] - m_[i]) * sc + be_[i];
    }
  }

  const int tv = lane;
  const int tv2 = lane + 64;
  const int tv2c = (tv2 < 100) ? tv2 : 99;  // clamped (results masked)

  // M accumulators: 4x4 (v,w) tile, threads 0..48 active (7x7 tile grid)
  float macc[4][4];
#pragma unroll
  for (int i = 0; i < 4; ++i)
#pragma unroll
    for (int j = 0; j < 4; ++j) macc[i][j] = 0.f;
  const int vg = tid / 7, wg = tid % 7;
  const int mv0 = vg * 4, mw0 = wg * 4;

  for (int chunk = 0; chunk < 15; ++chunk) {
    const int t0 = t_blk + chunk * 4;
    __syncthreads();
    // load x[n, :, t0..t0+3, :] -> x_lds[c][0..99]  (float4, coalesced)
    {
      const float4* src =
          reinterpret_cast<const float4*>(x + (size_t)n * 480000 + (size_t)t0 * 25);
      float4* dst = reinterpret_cast<float4*>(x_lds);
      for (int e = tid; e < 1600; e += 256) {
        int c = e / 25, q = e - c * 25;
        dst[c * 25 + q] = src[(size_t)c * 1875 + q];
      }
    }
    __syncthreads();
    // skinny GEMM: this wave's 8 rows x 100 tv, K=64
    {
      float acc[8][2];
#pragma unroll
      for (int r = 0; r < 8; ++r) { acc[r][0] = 0.f; acc[r][1] = 0.f; }
      for (int cc = 0; cc < 8; ++cc) {
        float wreg[8][8];
#pragma unroll
        for (int r = 0; r < 8; ++r)
#pragma unroll
          for (int k = 0; k < 8; ++k) wreg[r][k] = W[r * 64 + cc * 8 + k];
#pragma unroll
        for (int k = 0; k < 8; ++k) {
          int c = cc * 8 + k;
          float xv = x_lds[c * 100 + tv];
          float xv2 = x_lds[c * 100 + tv2c];
#pragma unroll
          for (int r = 0; r < 8; ++r) {
            acc[r][0] = fmaf(wreg[r][k], xv, acc[r][0]);
            acc[r][1] = fmaf(wreg[r][k], xv2, acc[r][1]);
          }
        }
      }
      float* dst = ab_lds + (size_t)(isB * 16 + r0) * 100;
#pragma unroll
      for (int r = 0; r < 8; ++r) {
        dst[r * 100 + tv] = tanhf(fmaf(acc[r][0], scv[r], shv[r]));
        if (tv2 < 100)
          dst[r * 100 + tv2] = tanhf(fmaf(acc[r][1], scv[r], shv[r]));
      }
    }
    __syncthreads();
    // M accumulation: M[v][w] += sum_{i,t} a[i][t,v]*b[i][t,w]
    if (tid < 49) {
      for (int i = 0; i < 16; ++i) {
        const float* arow = ab_lds + i * 100;
        const float* brow = ab_lds + (16 + i) * 100;
#pragma unroll
        for (int t = 0; t < 4; ++t) {
          float av[4], bv[4];
#pragma unroll
          for (int d = 0; d < 4; ++d) {
            av[d] = arow[t * 25 + mv0 + d];
            bv[d] = brow[t * 25 + mw0 + d];
          }
#pragma unroll
          for (int dv = 0; dv < 4; ++dv)
#pragma unroll
            for (int dw = 0; dw < 4; ++dw)
              macc[dv][dw] = fmaf(av[dv], bv[dw], macc[dv][dw]);
        }
      }
    }
  }
  if (tid < 49) {
    float* Mrow = Mbuf + (size_t)(n * 3 + s) * 625;
#pragma unroll
    for (int dv = 0; dv < 4; ++dv) {
      int v = mv0 + dv;
      if (v < 25) {
#pragma unroll
        for (int dw = 0; dw < 4; ++dw) {
          int w = mw0 + dw;
          if (w < 25) atomicAdd(Mrow + v * 25 + w, macc[dv][dw]);
        }
      }
    }
  }
}

// ---------------------------------------------------------------------------
// k_adp: A_adp = A + tanh(M/4800)*alpha
// ---------------------------------------------------------------------------
__global__ __launch_bounds__(256) void k_adp(const float* __restrict__ Mbuf,
                                             const float* __restrict__ A,
                                             const float* __restrict__ alpha,
                                             float* __restrict__ Aadp) {
  int idx = blockIdx.x * 256 + threadIdx.x;
  if (idx < 120000) {
    int vw = idx % 625;
    int s = (idx / 625) % 3;
    Aadp[idx] = A[s * 625 + vw] + tanhf(Mbuf[idx] * (1.0f / 4800.0f)) * alpha[0];
  }
}

// ---------------------------------------------------------------------------
// k_y: y[n,o,t,w] = sum_{s,c} wd[s,o,c] * (sum_v x[n,c,t,v]*Aadp[n,s,v,w])
//      out = relu(bn(y + db_sum) + x)
// grid (60 t-chunks, 64 n), block 320 (5 waves; wave = one t).
// ---------------------------------------------------------------------------
__global__ __launch_bounds__(320) void k_y(
    const float* __restrict__ x, const float* __restrict__ Aadp,
    const float* __restrict__ wdT, const float* __restrict__ db,
    const float* __restrict__ bng, const float* __restrict__ bnb,
    const float* __restrict__ bnm, const float* __restrict__ bnv,
    float* __restrict__ out) {
  __shared__ float xT[125 * 64];      // [tv][c ^ (tv&63)] swizzled transpose
  __shared__ float xm[5 * 64 * 36];   // [t][c][w], row padded to 36

  const int tid = threadIdx.x;
  const int lane = tid & 63;
  const int tt = tid >> 6;  // wave id == local t (0..4)
  const int n = blockIdx.y;
  const int tb = blockIdx.x * 5;
  const int t = tb + tt;

  // load + transpose x[n, :, tb..tb+4, :] (coalesced reads, swizzled writes)
  const float* xn = x + (size_t)n * 480000;
  for (int e = tid; e < 8000; e += 320) {
    int c = e / 125, tv = e - c * 125;
    xT[tv * 64 + (c ^ (tv & 63))] = xn[(size_t)c * 7500 + (size_t)tb * 25 + tv];
  }
  __syncthreads();

  const int lo = lane & 7, lw = lane >> 3;
  const int o0 = lo * 8, w0 = lw * 4;
  const int c = lane;  // stage-1 role of this lane

  // hoist this lane's x row (reused for all 3 s)
  float xreg[25];
#pragma unroll
  for (int v = 0; v < 25; ++v) {
    int tvv = tt * 25 + v;
    xreg[v] = xT[tvv * 64 + (c ^ (tvv & 63))];
  }

  float y[8][4];
#pragma unroll
  for (int r = 0; r < 8; ++r)
#pragma unroll
    for (int j = 0; j < 4; ++j) y[r][j] = 0.f;

  for (int s = 0; s < 3; ++s) {
    // ---- stage 1: xm[c][w] = sum_v x[c][t][v] * Aadp[n,s,v,w]
    float pacc[25];
#pragma unroll
    for (int w = 0; w < 25; ++w) pacc[w] = 0.f;
    const float* Aas = Aadp + (size_t)(n * 3 + s) * 625;
    for (int v = 0; v < 25; ++v) {
      float xr = xreg[v];
      const float* Ar = Aas + v * 25;  // wave-uniform -> s_loads
#pragma unroll
      for (int w = 0; w < 25; ++w) pacc[w] = fmaf(xr, Ar[w], pacc[w]);
    }
    float* xrow = xm + (size_t)(tt * 64 + c) * 36;
    float4* xrow4 = reinterpret_cast<float4*>(xrow);
#pragma unroll
    for (int q = 0; q < 6; ++q)
      xrow4[q] = make_float4(pacc[q * 4], pacc[q * 4 + 1], pacc[q * 4 + 2],
                             pacc[q * 4 + 3]);
    xrow[24] = pacc[24];

    // ---- stage 2: y[o][w] += sum_c wdT[s][c][o] * xm[c][w]
    const float4* wd4 = reinterpret_cast<const float4*>(wdT + (size_t)s * 4096);
    const float4* xm4 = reinterpret_cast<const float4*>(xm + (size_t)tt * 64 * 36);
    for (int cc = 0; cc < 64; ++cc) {
      float4 wA = wd4[cc * 16 + lo * 2];
      float4 wB = wd4[cc * 16 + lo * 2 + 1];
      float4 xv = xm4[cc * 9 + lw];
      float wr[8] = {wA.x, wA.y, wA.z, wA.w, wB.x, wB.y, wB.z, wB.w};
      float xj[4] = {xv.x, xv.y, xv.z, xv.w};
#pragma unroll
      for (int r = 0; r < 8; ++r)
#pragma unroll
        for (int j = 0; j < 4; ++j) y[r][j] = fmaf(wr[r], xj[j], y[r][j]);
    }
  }

  // ---- epilogue: bn + residual + relu
  float* outn = out + (size_t)n * 64 * 7500;
#pragma unroll
  for (int r = 0; r < 8; ++r) {
    int o = o0 + r;
    float sc = bng[o] * rsqrtf(bnv[o] + EPSf);
    float sh = (db[o] + db[64 + o] + db[128 + o] - bnm[o]) * sc + bnb[o];
#pragma unroll
    for (int j = 0; j < 4; ++j) {
      int w = w0 + j;
      if (w < 25) {
        int tvv = tt * 25 + w;
        float xrv = xT[tvv * 64 + (o ^ (tvv & 63))];
        float val = fmaf(y[r][j], sc, sh) + xrv;
        outn[(size_t)o * 7500 + (size_t)t * 25 + w] = fmaxf(val, 0.f);
      }
    }
  }
}

// ---------------------------------------------------------------------------
extern "C" void kernel_launch(void* const* d_in, const int* in_sizes, int n_in,
                              void* d_out, int out_size, void* d_ws,
                              size_t ws_size, hipStream_t stream) {
  const float* x = (const float*)d_in[0];
  const float* A = (const float*)d_in[1];
  const float* alpha = (const float*)d_in[2];
  const float* wa = (const float*)d_in[3];
  const float* wab = (const float*)d_in[4];
  const float* wb = (const float*)d_in[5];
  const float* wbb = (const float*)d_in[6];
  const float* ga = (const float*)d_in[7];
  const float* bea = (const float*)d_in[8];
  const float* ma = (const float*)d_in[9];
  const float* va = (const float*)d_in[10];
  const float* gb = (const float*)d_in[11];
  const float* beb = (const float*)d_in[12];
  const float* mb = (const float*)d_in[13];
  const float* vb = (const float*)d_in[14];
  const float* wd = (const float*)d_in[15];
  const float* db = (const float*)d_in[16];
  const float* bng = (const float*)d_in[17];
  const float* bnb = (const float*)d_in[18];
  const float* bnm = (const float*)d_in[19];
  const float* bnv = (const float*)d_in[20];

  float* ws = (float*)d_ws;
  float* Mbuf = ws;            // 120000 floats
  float* Aadp = ws + 120000;   // 120000 floats
  float* wdT = ws + 240000;    // 12288 floats

  hipMemsetAsync(Mbuf, 0, 120000 * sizeof(float), stream);
  k_tr<<<48, 256, 0, stream>>>(wd, wdT);
  k_M<<<dim3(5, 3, 64), 256, 0, stream>>>(x, wa, wab, wb, wbb, ga, bea, ma, va,
                                          gb, beb, mb, vb, Mbuf);
  k_adp<<<469, 256, 0, stream>>>(Mbuf, A, alpha, Aadp);
  k_y<<<dim3(60, 64), 320, 0, stream>>>(x, Aadp, wdT, db, bng, bnb, bnm, bnv,
                                        (float*)d_out);
}

// Round 3
// 480.240 us; speedup vs baseline: 2.4757x; 2.4757x over previous
//
#include <hip/hip_runtime.h>
#include <math.h>

typedef __attribute__((ext_vector_type(8))) short bf16x8;
typedef __attribute__((ext_vector_type(4))) float f32x4;
typedef __attribute__((ext_vector_type(4))) unsigned short us4;

__device__ inline unsigned short f2bf(float f) {
  union { float f; unsigned u; } v; v.f = f;
  return (unsigned short)((v.u + 0x7FFF + ((v.u >> 16) & 1)) >> 16);
}
__device__ inline float tanh_fast(float x) {
  // tanh(x) = 1 - 2/(exp2(x*2*log2e)+1); v_exp_f32 + v_rcp_f32
  return 1.0f - 2.0f * __builtin_amdgcn_rcpf(
                           __builtin_amdgcn_exp2f(x * 2.885390081777927f) + 1.0f);
}

// ---------------------------------------------------------------------------
// k_xT: x (n,c,tv) fp32 -> xTg (n,tv,c) bf16.  xTg lives in d_out (scratch).
// ---------------------------------------------------------------------------
__global__ __launch_bounds__(256) void k_xT(const float* __restrict__ x,
                                            unsigned short* __restrict__ xTg) {
  __shared__ float xt[125 * 65];
  const int tid = threadIdx.x, n = blockIdx.y, tb = blockIdx.x * 125;
  const float* xn = x + (size_t)n * 480000;
  for (int e = tid; e < 8000; e += 256) {
    int c = e / 125, i = e - c * 125;
    xt[i * 65 + c] = xn[(size_t)c * 7500 + tb + i];
  }
  __syncthreads();
  unsigned short* dst = xTg + ((size_t)n * 7500 + tb) * 64;
  for (int e = tid; e < 8000; e += 256) {
    int i = e >> 6, c = e & 63;
    dst[(size_t)i * 64 + c] = f2bf(xt[i * 65 + c]);
  }
}

// ---------------------------------------------------------------------------
// k_M: per (s, Trange=60t, n): GEMM1 [a;b] = tanh(bn(W @ x)) via MFMA
//      (B-frags from xTg global), then GEMM2 M += A'^T B' (K'=16*15/chunk).
// block 256 = 4 waves; LDS = ab2 only (32 KB).
// ---------------------------------------------------------------------------
__global__ __launch_bounds__(256) void k_M(
    const unsigned short* __restrict__ xTg,
    const float* __restrict__ wa, const float* __restrict__ wab,
    const float* __restrict__ wb, const float* __restrict__ wbb,
    const float* __restrict__ ga, const float* __restrict__ bea,
    const float* __restrict__ ma, const float* __restrict__ va,
    const float* __restrict__ gb, const float* __restrict__ beb,
    const float* __restrict__ mb, const float* __restrict__ vb,
    float* __restrict__ Mbuf) {
  __shared__ unsigned short ab2[2][32 * 256];  // [a/b][v-row][k'=(t_l*16+i)]
  const int tid = threadIdx.x, lane = tid & 63;
  const int wid = tid >> 6;
  const int s = blockIdx.x, bx = blockIdx.y, n = blockIdx.z;
  const int l15 = lane & 15, lg = lane >> 4;

  // zero ab2 (pad k' 240..255 and rows v>=25 must read as 0)
  for (int e = tid; e < 4096; e += 256) ((unsigned long long*)ab2)[e] = 0ull;

  // A-frags: W[row=i=l15][k=c], 2 K-steps, rt: 0=a,1=b
  bf16x8 afrag[2][2];
#pragma unroll
  for (int rt = 0; rt < 2; ++rt) {
    const float* W = (rt ? wb : wa) + ((size_t)s * 16 + l15) * 64;
#pragma unroll
    for (int Ks = 0; Ks < 2; ++Ks) {
      const float* p = W + Ks * 32 + lg * 8;
      bf16x8 f;
#pragma unroll
      for (int j = 0; j < 8; ++j) f[j] = (short)f2bf(p[j]);
      afrag[rt][Ks] = f;
    }
  }

  // bn fold for rows i = lg*4 + r
  float scv[2][4], shv[2][4];
#pragma unroll
  for (int r = 0; r < 4; ++r) {
    int i = s * 16 + lg * 4 + r;
    float sc = ga[i] * rsqrtf(va[i] + 1e-5f);
    scv[0][r] = sc; shv[0][r] = (wab[i] - ma[i]) * sc + bea[i];
    sc = gb[i] * rsqrtf(vb[i] + 1e-5f);
    scv[1][r] = sc; shv[1][r] = (wbb[i] - mb[i]) * sc + beb[i];
  }

  const int vt = wid >> 1, wt = wid & 1;  // GEMM2 tile of this wave
  f32x4 facc = {0.f, 0.f, 0.f, 0.f};
  const unsigned short* xbase = xTg + (size_t)n * 7500 * 64;

  for (int chunk = 0; chunk < 4; ++chunk) {
    const int tvb = (bx * 4 + chunk) * 375;
    __syncthreads();  // ab2 free (previous GEMM2 done)
    // ---- GEMM1: wave handles 6 col-tiles of 16 (384 cols, 375 valid)
#pragma unroll
    for (int ct = 0; ct < 6; ++ct) {
      int col = (wid * 6 + ct) * 16 + l15;
      bool valid = col < 375;
      int colc = valid ? col : 374;
      const unsigned short* bp = xbase + (size_t)(tvb + colc) * 64 + lg * 8;
      bf16x8 bf0 = *(const bf16x8*)bp;
      bf16x8 bf1 = *(const bf16x8*)(bp + 32);
      int tl = colc / 25, v = colc - tl * 25;
      int kp = tl * 16 + lg * 4;
#pragma unroll
      for (int rt = 0; rt < 2; ++rt) {
        f32x4 d = {0.f, 0.f, 0.f, 0.f};
        d = __builtin_amdgcn_mfma_f32_16x16x32_bf16(afrag[rt][0], bf0, d, 0, 0, 0);
        d = __builtin_amdgcn_mfma_f32_16x16x32_bf16(afrag[rt][1], bf1, d, 0, 0, 0);
        if (valid) {
          us4 pk;
#pragma unroll
          for (int r = 0; r < 4; ++r)
            pk[r] = f2bf(tanh_fast(d[r] * scv[rt][r] + shv[rt][r]));
          unsigned byte = ((unsigned)(v * 256 + kp) * 2) ^ ((v & 7) << 4);
          *(us4*)((char*)ab2[rt] + byte) = pk;
        }
      }
    }
    __syncthreads();
    // ---- GEMM2: wave computes its (vt,wt) 16x16 tile, K'=256 (zero-padded)
#pragma unroll
    for (int ks = 0; ks < 8; ++ks) {
      int va_ = vt * 16 + l15, wa_ = wt * 16 + l15;
      unsigned ab_ = ((unsigned)(va_ * 256 + lg * 8 + ks * 32) * 2) ^ ((va_ & 7) << 4);
      unsigned bb_ = ((unsigned)(wa_ * 256 + lg * 8 + ks * 32) * 2) ^ ((wa_ & 7) << 4);
      bf16x8 af = *(bf16x8*)((char*)ab2[0] + ab_);
      bf16x8 bf = *(bf16x8*)((char*)ab2[1] + bb_);
      facc = __builtin_amdgcn_mfma_f32_16x16x32_bf16(af, bf, facc, 0, 0, 0);
    }
  }
  const int w = wt * 16 + l15;
  if (w < 25) {
    float* Mrow = Mbuf + ((size_t)n * 3 + s) * 625;
#pragma unroll
    for (int r = 0; r < 4; ++r) {
      int v = vt * 16 + lg * 4 + r;
      if (v < 25) atomicAdd(Mrow + v * 25 + w, facc[r]);
    }
  }
}

// ---------------------------------------------------------------------------
// k_adp: A_adp = A + tanh(M/4800)*alpha
// ---------------------------------------------------------------------------
__global__ __launch_bounds__(256) void k_adp(const float* __restrict__ Mbuf,
                                             const float* __restrict__ A,
                                             const float* __restrict__ alpha,
                                             float* __restrict__ Aadp) {
  int idx = blockIdx.x * 256 + threadIdx.x;
  if (idx < 120000) {
    int vw = idx % 625;
    int s = (idx / 625) % 3;
    Aadp[idx] = A[s * 625 + vw] + tanh_fast(Mbuf[idx] * (1.0f / 4800.0f)) * alpha[0];
  }
}

// ---------------------------------------------------------------------------
// k_y: per (n, 10-t chunk): xm-GEMM (A=Aadp^T LDS, B=x-rows regs) -> xmT LDS
//      -> y-GEMM (A=wd, accumulate over s) -> bn+residual+relu epilogue.
// block 256 = 4 waves; wave = c-quarter (xm) / o-quarter (y).
// ---------------------------------------------------------------------------
__global__ __launch_bounds__(256) void k_y(
    const float* __restrict__ x, const float* __restrict__ Aadp,
    const float* __restrict__ wd, const float* __restrict__ db,
    const float* __restrict__ bng, const float* __restrict__ bnb,
    const float* __restrict__ bnm, const float* __restrict__ bnv,
    float* __restrict__ out) {
  __shared__ unsigned short xmT[256 * 64];    // [tw][c], XOR-swizzled rows
  __shared__ unsigned short AaT[3][32 * 40];  // [s][w][v], padded row 40
  const int tid = threadIdx.x, lane = tid & 63, wid = tid >> 6;
  const int l15 = lane & 15, lg = lane >> 4;
  const int bx = blockIdx.x, n = blockIdx.y;
  const int t0 = bx * 10;

  for (int e = tid; e < 3 * 32 * 40 / 4; e += 256) ((unsigned long long*)AaT)[e] = 0ull;
  __syncthreads();
  const float* Aan = Aadp + (size_t)n * 1875;
  for (int e = tid; e < 1875; e += 256) {
    int s = e / 625, r = e - s * 625, v = r / 25, w = r - v * 25;
    AaT[s][w * 40 + v] = f2bf(Aan[e]);
  }

  // bn consts for rows o = wid*16 + lg*4 + r
  float sc4[4], sh4[4];
#pragma unroll
  for (int r = 0; r < 4; ++r) {
    int o = wid * 16 + lg * 4 + r;
    float sc = bng[o] * rsqrtf(bnv[o] + 1e-5f);
    sc4[r] = sc;
    sh4[r] = (db[o] + db[64 + o] + db[128 + o] - bnm[o]) * sc + bnb[o];
  }

  // cache x B-frags (B^T[col=c][k=v], v>=25 zero), reused for all 3 s
  const float* xn = x + (size_t)n * 480000;
  bf16x8 xfrag[10];
  {
    const int c = wid * 16 + l15;
    const float* xr = xn + (size_t)c * 7500 + t0 * 25;
#pragma unroll
    for (int t = 0; t < 10; ++t) {
      bf16x8 f;
#pragma unroll
      for (int j = 0; j < 8; ++j) {
        int v = lg * 8 + j;
        f[j] = (v < 25) ? (short)f2bf(xr[t * 25 + v]) : (short)0;
      }
      xfrag[t] = f;
    }
  }
  __syncthreads();  // AaT ready

  f32x4 yacc[16];
#pragma unroll
  for (int i = 0; i < 16; ++i) yacc[i] = (f32x4){0.f, 0.f, 0.f, 0.f};

  for (int s = 0; s < 3; ++s) {
    // ---- xm-GEMM: D[w][c] = sum_v Aadp^T[w][v] * x[c][t,v]; wave owns c-quarter
    bf16x8 af0 = *(bf16x8*)(&AaT[s][l15 * 40 + lg * 8]);
    bf16x8 af1 = *(bf16x8*)(&AaT[s][(16 + l15) * 40 + lg * 8]);
    const int c = wid * 16 + l15;
#pragma unroll
    for (int t = 0; t < 10; ++t) {
#pragma unroll
      for (int wt = 0; wt < 2; ++wt) {
        f32x4 d = {0.f, 0.f, 0.f, 0.f};
        d = __builtin_amdgcn_mfma_f32_16x16x32_bf16(wt ? af1 : af0, xfrag[t], d, 0, 0, 0);
#pragma unroll
        for (int r = 0; r < 4; ++r) {
          int w = wt * 16 + lg * 4 + r;
          if (w < 25) {
            int tw = t * 25 + w;
            unsigned byte = ((unsigned)(tw * 64 + c) * 2) ^ ((tw & 7) << 4);
            *(unsigned short*)((char*)xmT + byte) = f2bf(d[r]);
          }
        }
      }
    }
    __syncthreads();
    // ---- y-GEMM: wave owns o-quarter (rows o = wid*16+..)
    bf16x8 wf0, wf1;
    {
      const float* wp = wd + ((size_t)s * 64 + wid * 16 + l15) * 64 + lg * 8;
#pragma unroll
      for (int j = 0; j < 8; ++j) {
        wf0[j] = (short)f2bf(wp[j]);
        wf1[j] = (short)f2bf(wp[32 + j]);
      }
    }
#pragma unroll
    for (int ct = 0; ct < 16; ++ct) {
      int tw = ct * 16 + l15;
      unsigned b0 = ((unsigned)(tw * 64 + lg * 8) * 2) ^ ((tw & 7) << 4);
      unsigned b1 = ((unsigned)(tw * 64 + 32 + lg * 8) * 2) ^ ((tw & 7) << 4);
      bf16x8 xb0 = *(bf16x8*)((char*)xmT + b0);
      bf16x8 xb1 = *(bf16x8*)((char*)xmT + b1);
      yacc[ct] = __builtin_amdgcn_mfma_f32_16x16x32_bf16(wf0, xb0, yacc[ct], 0, 0, 0);
      yacc[ct] = __builtin_amdgcn_mfma_f32_16x16x32_bf16(wf1, xb1, yacc[ct], 0, 0, 0);
    }
    __syncthreads();  // xmT reused next s
  }

  // ---- epilogue: bn + residual + relu
  float* outn = out + (size_t)n * 480000;
#pragma unroll
  for (int ct = 0; ct < 16; ++ct) {
    int tw = ct * 16 + l15;
    if (tw < 250) {
      int t = tw / 25, w = tw - t * 25;
      size_t base = (size_t)(t0 + t) * 25 + w;
#pragma unroll
      for (int r = 0; r < 4; ++r) {
        int o = wid * 16 + lg * 4 + r;
        size_t addr = (size_t)o * 7500 + base;
        float val = yacc[ct][r] * sc4[r] + sh4[r] + xn[addr];
        outn[addr] = fmaxf(val, 0.f);
      }
    }
  }
}

// ---------------------------------------------------------------------------
extern "C" void kernel_launch(void* const* d_in, const int* in_sizes, int n_in,
                              void* d_out, int out_size, void* d_ws,
                              size_t ws_size, hipStream_t stream) {
  const float* x = (const float*)d_in[0];
  const float* A = (const float*)d_in[1];
  const float* alpha = (const float*)d_in[2];
  const float* wa = (const float*)d_in[3];
  const float* wab = (const float*)d_in[4];
  const float* wb = (const float*)d_in[5];
  const float* wbb = (const float*)d_in[6];
  const float* ga = (const float*)d_in[7];
  const float* bea = (const float*)d_in[8];
  const float* ma = (const float*)d_in[9];
  const float* va = (const float*)d_in[10];
  const float* gb = (const float*)d_in[11];
  const float* beb = (const float*)d_in[12];
  const float* mb = (const float*)d_in[13];
  const float* vb = (const float*)d_in[14];
  const float* wd = (const float*)d_in[15];
  const float* db = (const float*)d_in[16];
  const float* bng = (const float*)d_in[17];
  const float* bnb = (const float*)d_in[18];
  const float* bnm = (const float*)d_in[19];
  const float* bnv = (const float*)d_in[20];

  float* ws = (float*)d_ws;
  float* Mbuf = ws;           // 120000 floats
  float* Aadp = ws + 120000;  // 120000 floats
  // xTg scratch lives in d_out (61.44 MB of its 122.88 MB); k_y rewrites d_out.
  unsigned short* xTg = (unsigned short*)d_out;

  hipMemsetAsync(Mbuf, 0, 120000 * sizeof(float), stream);
  k_xT<<<dim3(60, 64), 256, 0, stream>>>(x, xTg);
  k_M<<<dim3(3, 5, 64), 256, 0, stream>>>(xTg, wa, wab, wb, wbb, ga, bea, ma,
                                          va, gb, beb, mb, vb, Mbuf);
  k_adp<<<469, 256, 0, stream>>>(Mbuf, A, alpha, Aadp);
  k_y<<<dim3(30, 64), 256, 0, stream>>>(x, Aadp, wd, db, bng, bnb, bnm, bnv,
                                        (float*)d_out);
}

// Round 4
// 411.229 us; speedup vs baseline: 2.8911x; 1.1678x over previous
//
#include <hip/hip_runtime.h>
#include <math.h>

typedef __attribute__((ext_vector_type(8))) short bf16x8;
typedef __attribute__((ext_vector_type(4))) float f32x4;
typedef __attribute__((ext_vector_type(4))) unsigned short us4;

__device__ inline unsigned short f2bf(float f) {
  union { float f; unsigned u; } v; v.f = f;
  return (unsigned short)((v.u + 0x7FFF + ((v.u >> 16) & 1)) >> 16);
}
__device__ inline float bf2f(unsigned short b) {
  union { unsigned u; float f; } v; v.u = ((unsigned)b) << 16;
  return v.f;
}
__device__ inline float tanh_fast(float x) {
  return 1.0f - 2.0f * __builtin_amdgcn_rcpf(
                           __builtin_amdgcn_exp2f(x * 2.885390081777927f) + 1.0f);
}

// ---------------------------------------------------------------------------
// k_prep: wd (S,OC,C) fp32 -> bf16 (same layout; y-GEMM A-frag wants [o][c]).
// ---------------------------------------------------------------------------
__global__ __launch_bounds__(256) void k_prep(const float* __restrict__ wd,
                                              unsigned short* __restrict__ wdb) {
  int idx = blockIdx.x * 256 + threadIdx.x;
  if (idx < 12288) wdb[idx] = f2bf(wd[idx]);
}

// ---------------------------------------------------------------------------
// k_xT: x (n,c,tv) fp32 -> xTg (n,tv,c) bf16 (lives in d_out scratch).
// ---------------------------------------------------------------------------
__global__ __launch_bounds__(256) void k_xT(const float* __restrict__ x,
                                            unsigned short* __restrict__ xTg) {
  __shared__ float xt[125 * 65];
  const int tid = threadIdx.x, n = blockIdx.y, tb = blockIdx.x * 125;
  const float* xn = x + (size_t)n * 480000;
  for (int e = tid; e < 8000; e += 256) {
    int c = e / 125, i = e - c * 125;
    xt[i * 65 + c] = xn[(size_t)c * 7500 + tb + i];
  }
  __syncthreads();
  unsigned short* dst = xTg + ((size_t)n * 7500 + tb) * 64;
  for (int e = tid; e < 8000; e += 256) {
    int i = e >> 6, c = e & 63;
    dst[(size_t)i * 64 + c] = f2bf(xt[i * 65 + c]);
  }
}

// ---------------------------------------------------------------------------
// k_M: per (bx=10, n): 3 chunks of 250 tv; stage xTg tile -> LDS (swizzled);
// for s in 0..2: GEMM1 [a;b]=tanh(bn(W@x)) -> ab2 LDS; GEMM2 M_s += a^T b.
// block 256 = 4 waves. LDS 32000 + 24576 = 55.3 KB -> 2 blocks/CU.
// ---------------------------------------------------------------------------
__global__ __launch_bounds__(256) void k_M(
    const unsigned short* __restrict__ xTg,
    const float* __restrict__ wa, const float* __restrict__ wab,
    const float* __restrict__ wb, const float* __restrict__ wbb,
    const float* __restrict__ ga, const float* __restrict__ bea,
    const float* __restrict__ ma, const float* __restrict__ va,
    const float* __restrict__ gb, const float* __restrict__ beb,
    const float* __restrict__ mb, const float* __restrict__ vb,
    float* __restrict__ Mbuf) {
  __shared__ unsigned short xt[250 * 64];       // [tv][c], XOR-swizzled
  __shared__ unsigned short ab2[2][32 * 192];   // [a/b][v][k'=tl*16+i], swz

  const int tid = threadIdx.x, lane = tid & 63, wid = tid >> 6;
  const int l15 = lane & 15, lg = lane >> 4;
  const int bx = blockIdx.x, n = blockIdx.y;

  // zero ab2 once (v>=25 rows and k'>=160 pads must stay 0)
  for (int e = tid; e < 3072; e += 256) ((unsigned long long*)ab2)[e] = 0ull;

  // A-frags (rows i=l15, k=c): [s][rt][Ks]
  bf16x8 afrag[3][2][2];
#pragma unroll
  for (int s = 0; s < 3; ++s)
#pragma unroll
    for (int rt = 0; rt < 2; ++rt) {
      const float* W = (rt ? wb : wa) + ((size_t)s * 16 + l15) * 64;
#pragma unroll
      for (int Ks = 0; Ks < 2; ++Ks) {
        bf16x8 f;
        const float* p = W + Ks * 32 + lg * 8;
#pragma unroll
        for (int j = 0; j < 8; ++j) f[j] = (short)f2bf(p[j]);
        afrag[s][rt][Ks] = f;
      }
    }
  // bn folds for rows i = lg*4 + r
  float scv[3][2][4], shv[3][2][4];
#pragma unroll
  for (int s = 0; s < 3; ++s)
#pragma unroll
    for (int r = 0; r < 4; ++r) {
      int i = s * 16 + lg * 4 + r;
      float sc = ga[i] * rsqrtf(va[i] + 1e-5f);
      scv[s][0][r] = sc; shv[s][0][r] = (wab[i] - ma[i]) * sc + bea[i];
      sc = gb[i] * rsqrtf(vb[i] + 1e-5f);
      scv[s][1][r] = sc; shv[s][1][r] = (wbb[i] - mb[i]) * sc + beb[i];
    }

  const int vt = wid >> 1, wt = wid & 1;
  f32x4 facc[3];
#pragma unroll
  for (int s = 0; s < 3; ++s) facc[s] = (f32x4){0.f, 0.f, 0.f, 0.f};
  const unsigned short* xbase = xTg + (size_t)n * 480000;

  for (int chunk = 0; chunk < 3; ++chunk) {
    const int tvb = (bx * 3 + chunk) * 250;
    __syncthreads();  // ab2-zero visible / prev GEMM2 done / xt free
    // stage xTg tile -> xt (2000 x 16B units, coalesced, swizzled dest)
    for (int u = tid; u < 2000; u += 256) {
      int tv = u >> 3, q = u & 7;
      bf16x8 val = *(const bf16x8*)(xbase + (size_t)(tvb + tv) * 64 + q * 8);
      *(bf16x8*)((char*)xt + ((tv * 128 + q * 16) ^ ((tv & 7) << 4))) = val;
    }
    __syncthreads();
#pragma unroll
    for (int s = 0; s < 3; ++s) {
      // ---- GEMM1: wave covers 4 col-tiles of 16 (256>=250)
#pragma unroll
      for (int ct = 0; ct < 4; ++ct) {
        int col = (wid * 4 + ct) * 16 + l15;
        int colc = (col < 250) ? col : 249;
        bf16x8 bf0 = *(bf16x8*)((char*)xt + ((colc * 128 + lg * 16) ^ ((colc & 7) << 4)));
        bf16x8 bf1 = *(bf16x8*)((char*)xt + ((colc * 128 + 64 + lg * 16) ^ ((colc & 7) << 4)));
        int tl = (colc * 41) >> 10, v = colc - tl * 25;
        int kp = tl * 16 + lg * 4;
#pragma unroll
        for (int rt = 0; rt < 2; ++rt) {
          f32x4 d = {0.f, 0.f, 0.f, 0.f};
          d = __builtin_amdgcn_mfma_f32_16x16x32_bf16(afrag[s][rt][0], bf0, d, 0, 0, 0);
          d = __builtin_amdgcn_mfma_f32_16x16x32_bf16(afrag[s][rt][1], bf1, d, 0, 0, 0);
          if (col < 250) {
            us4 pk;
#pragma unroll
            for (int r = 0; r < 4; ++r)
              pk[r] = f2bf(tanh_fast(d[r] * scv[s][rt][r] + shv[s][rt][r]));
            *(us4*)((char*)ab2[rt] + ((v * 384 + kp * 2) ^ ((v & 7) << 4))) = pk;
          }
        }
      }
      __syncthreads();
      // ---- GEMM2: wave (vt,wt) quadrant, K'=192 (zero-padded)
#pragma unroll
      for (int ks = 0; ks < 6; ++ks) {
        int va_ = vt * 16 + l15, wa_ = wt * 16 + l15;
        bf16x8 af = *(bf16x8*)((char*)ab2[0] + ((va_ * 384 + ks * 64 + lg * 16) ^ ((va_ & 7) << 4)));
        bf16x8 bf = *(bf16x8*)((char*)ab2[1] + ((wa_ * 384 + ks * 64 + lg * 16) ^ ((wa_ & 7) << 4)));
        facc[s] = __builtin_amdgcn_mfma_f32_16x16x32_bf16(af, bf, facc[s], 0, 0, 0);
      }
      __syncthreads();
    }
  }
  const int w = wt * 16 + l15;
  if (w < 25) {
#pragma unroll
    for (int s = 0; s < 3; ++s) {
      float* Mrow = Mbuf + ((size_t)n * 3 + s) * 625;
#pragma unroll
      for (int r = 0; r < 4; ++r) {
        int v = vt * 16 + lg * 4 + r;
        if (v < 25) atomicAdd(Mrow + v * 25 + w, facc[s][r]);
      }
    }
  }
}

// ---------------------------------------------------------------------------
// k_adp: AadpT[n,s,w,v] (bf16, 32x32 zero-padded) = (A + tanh(M/4800)*alpha)^T
// ---------------------------------------------------------------------------
__global__ __launch_bounds__(256) void k_adp(const float* __restrict__ Mbuf,
                                             const float* __restrict__ A,
                                             const float* __restrict__ alpha,
                                             unsigned short* __restrict__ AadpT) {
  int idx = blockIdx.x * 256 + threadIdx.x;
  if (idx < 196608) {
    int v = idx & 31, w = (idx >> 5) & 31, ns = idx >> 10;
    int s = ns % 3;
    float val = 0.f;
    if (v < 25 && w < 25)
      val = A[s * 625 + v * 25 + w] +
            tanh_fast(Mbuf[(size_t)ns * 625 + v * 25 + w] * (1.0f / 4800.0f)) * alpha[0];
    AadpT[idx] = f2bf(val);
  }
}

// ---------------------------------------------------------------------------
// k_y: per (n, 5-t chunk): stage x->LDS bf16 (coalesced, no transpose);
// xm-GEMM (A=x frags, B=AadpT) -> xmT LDS; y-GEMM (A=wd) accumulated over s;
// epilogue bn + bf16-residual + relu.  block 256 = 4 waves; LDS 36 KB.
// ---------------------------------------------------------------------------
__global__ __launch_bounds__(256) void k_y(
    const float* __restrict__ x, const unsigned short* __restrict__ AadpT,
    const unsigned short* __restrict__ wdb, const float* __restrict__ db,
    const float* __restrict__ bng, const float* __restrict__ bnb,
    const float* __restrict__ bnm, const float* __restrict__ bnv,
    float* __restrict__ out) {
  __shared__ unsigned short xc[64 * 160];   // [c][t*32+v], swz; 20480 B
  __shared__ unsigned short xmT[128 * 64];  // [tw][c], swz; 16384 B
  const int tid = threadIdx.x, lane = tid & 63, wid = tid >> 6;
  const int l15 = lane & 15, lg = lane >> 4;
  const int bx = blockIdx.x, n = blockIdx.y;
  const int t0 = bx * 5;

  // zero xc (v-pads must not be NaN garbage for MFMA k-slots)
  for (int e = tid; e < 2560; e += 256) ((unsigned long long*)xc)[e] = 0ull;
  __syncthreads();
  // stage x fp32 -> bf16 LDS, coalesced (rows of 125 contiguous floats)
  const float* xn = x + (size_t)n * 480000;
  for (int idx = tid; idx < 8192; idx += 256) {
    int c = idx >> 7, j = idx & 127;
    if (j < 125) {
      int t = (j * 41) >> 10, v = j - t * 25;
      unsigned short bv = f2bf(xn[(size_t)c * 7500 + t0 * 25 + j]);
      *(unsigned short*)((char*)xc + ((c * 320 + t * 64 + v * 2) ^ ((c & 7) << 4))) = bv;
    }
  }

  // bn consts for rows o = wid*16 + lg*4 + r
  float sc4[4], sh4[4];
#pragma unroll
  for (int r = 0; r < 4; ++r) {
    int o = wid * 16 + lg * 4 + r;
    float sc = bng[o] * rsqrtf(bnv[o] + 1e-5f);
    sc4[r] = sc;
    sh4[r] = (db[o] + db[64 + o] + db[128 + o] - bnm[o]) * sc + bnb[o];
  }
  __syncthreads();

  // x A-frags (row=c=wid*16+l15, k=v), one per t, reused for all s
  bf16x8 xf[5];
#pragma unroll
  for (int t = 0; t < 5; ++t)
    xf[t] = *(bf16x8*)((char*)xc +
                       (((wid * 16 + l15) * 320 + t * 64 + lg * 16) ^ ((l15 & 7) << 4)));

  f32x4 yacc[8];
#pragma unroll
  for (int i = 0; i < 8; ++i) yacc[i] = (f32x4){0.f, 0.f, 0.f, 0.f};

  for (int s = 0; s < 3; ++s) {
    // ---- xm-GEMM: D[c][w] = sum_v x[c][v] * AadpT[w][v]
    const unsigned short* Ab = AadpT + (((size_t)n * 3 + s) << 10);
    bf16x8 bA0 = *(const bf16x8*)(Ab + l15 * 32 + lg * 8);
    bf16x8 bA1 = *(const bf16x8*)(Ab + (16 + l15) * 32 + lg * 8);
#pragma unroll
    for (int t = 0; t < 5; ++t) {
#pragma unroll
      for (int wt = 0; wt < 2; ++wt) {
        f32x4 d = {0.f, 0.f, 0.f, 0.f};
        d = __builtin_amdgcn_mfma_f32_16x16x32_bf16(xf[t], wt ? bA1 : bA0, d, 0, 0, 0);
        int w = wt * 16 + l15;
        if (w < 25) {
          int tw = t * 25 + w;
          us4 pk;
#pragma unroll
          for (int r = 0; r < 4; ++r) pk[r] = f2bf(d[r]);
          *(us4*)((char*)xmT + ((tw * 128 + wid * 32 + lg * 8) ^ ((tw & 7) << 4))) = pk;
        }
      }
    }
    __syncthreads();
    // ---- y-GEMM: D[o][tw] += sum_c wd[o][c] * xmT[tw][c]
    const unsigned short* wp = wdb + ((size_t)s * 64 + wid * 16 + l15) * 64;
    bf16x8 wf0 = *(const bf16x8*)(wp + lg * 8);
    bf16x8 wf1 = *(const bf16x8*)(wp + 32 + lg * 8);
#pragma unroll
    for (int ct = 0; ct < 8; ++ct) {
      int tw = ct * 16 + l15;
      bf16x8 xb0 = *(bf16x8*)((char*)xmT + ((tw * 128 + lg * 16) ^ ((tw & 7) << 4)));
      bf16x8 xb1 = *(bf16x8*)((char*)xmT + ((tw * 128 + 64 + lg * 16) ^ ((tw & 7) << 4)));
      yacc[ct] = __builtin_amdgcn_mfma_f32_16x16x32_bf16(wf0, xb0, yacc[ct], 0, 0, 0);
      yacc[ct] = __builtin_amdgcn_mfma_f32_16x16x32_bf16(wf1, xb1, yacc[ct], 0, 0, 0);
    }
    __syncthreads();
  }

  // ---- epilogue: bn + residual(bf16 from LDS) + relu
  float* outn = out + (size_t)n * 480000;
#pragma unroll
  for (int ct = 0; ct < 8; ++ct) {
    int tw = ct * 16 + l15;
    if (tw < 125) {
      int t = (tw * 41) >> 10, w = tw - t * 25;
#pragma unroll
      for (int r = 0; r < 4; ++r) {
        int o = wid * 16 + lg * 4 + r;
        float res = bf2f(*(unsigned short*)(
            (char*)xc + ((o * 320 + t * 64 + w * 2) ^ ((o & 7) << 4))));
        float val = yacc[ct][r] * sc4[r] + sh4[r] + res;
        outn[(size_t)o * 7500 + (size_t)(t0 + t) * 25 + w] = fmaxf(val, 0.f);
      }
    }
  }
}

// ---------------------------------------------------------------------------
extern "C" void kernel_launch(void* const* d_in, const int* in_sizes, int n_in,
                              void* d_out, int out_size, void* d_ws,
                              size_t ws_size, hipStream_t stream) {
  const float* x = (const float*)d_in[0];
  const float* A = (const float*)d_in[1];
  const float* alpha = (const float*)d_in[2];
  const float* wa = (const float*)d_in[3];
  const float* wab = (const float*)d_in[4];
  const float* wb = (const float*)d_in[5];
  const float* wbb = (const float*)d_in[6];
  const float* ga = (const float*)d_in[7];
  const float* bea = (const float*)d_in[8];
  const float* ma = (const float*)d_in[9];
  const float* va = (const float*)d_in[10];
  const float* gb = (const float*)d_in[11];
  const float* beb = (const float*)d_in[12];
  const float* mb = (const float*)d_in[13];
  const float* vb = (const float*)d_in[14];
  const float* wd = (const float*)d_in[15];
  const float* db = (const float*)d_in[16];
  const float* bng = (const float*)d_in[17];
  const float* bnb = (const float*)d_in[18];
  const float* bnm = (const float*)d_in[19];
  const float* bnv = (const float*)d_in[20];

  char* ws = (char*)d_ws;
  float* Mbuf = (float*)ws;                              // 480000 B
  unsigned short* AadpT = (unsigned short*)(ws + 480000); // 393216 B
  unsigned short* wdb = (unsigned short*)(ws + 873216);   // 24576 B
  unsigned short* xTg = (unsigned short*)d_out;           // 61.4 MB scratch

  hipMemsetAsync(Mbuf, 0, 480000, stream);
  k_prep<<<48, 256, 0, stream>>>(wd, wdb);
  k_xT<<<dim3(60, 64), 256, 0, stream>>>(x, xTg);
  k_M<<<dim3(10, 64), 256, 0, stream>>>(xTg, wa, wab, wb, wbb, ga, bea, ma, va,
                                        gb, beb, mb, vb, Mbuf);
  k_adp<<<768, 256, 0, stream>>>(Mbuf, A, alpha, AadpT);
  k_y<<<dim3(60, 64), 256, 0, stream>>>(x, AadpT, wdb, db, bng, bnb, bnm, bnv,
                                        (float*)d_out);
}